// Round 4
// baseline (150.762 us; speedup 1.0000x reference)
//
#include <hip/hip_runtime.h>
#include <math.h>

// GaussianMixtureLayer: N=4194304 points (D=2), K=32 isotropic components.
// Outputs: mix_lp (N,) then comp_lp (N,32), concatenated float32.
// Memory-bound: ~587 MB traffic -> ~89 us floor at fill rate (6.6 TB/s).
//
// Layout: 8 lanes per point; lane j=tid&7 owns components 4j..4j+3 in regs.
// Thread i's comp_lp store address = base + 16B*i -> 1KB contiguous per wave.
// R4: 4 independent tiles/iter (deeper store pipeline); stores are REGULAR
// (L2 write-back merges partial lines; nt-store suspected of hurting R3),
// loads stay nontemporal (read-once stream). Bulk comp stores issue before
// the reduction tail.

constexpr float NEG_D_HALF_LOG2PI = -1.8378770664093453f; // -0.5*D*log(2pi), D=2
constexpr float LOG_K = 3.4657359027997265f;              // log(32)

typedef float vf2 __attribute__((ext_vector_type(2)));
typedef float vf4 __attribute__((ext_vector_type(4)));

__global__ __launch_bounds__(256) void gmm_kernel(
    const float* __restrict__ x,      // (N,2)
    const float* __restrict__ mu,     // (32,2)
    const float* __restrict__ sigma,  // (32,1)
    float* __restrict__ out,          // mix_lp (N) ++ comp_lp (N*32)
    int N)
{
    const int tid = threadIdx.x;
    const int j   = tid & 7;    // component sub-group: owns k = 4j..4j+3
    const int pg  = tid >> 3;   // point index within a 32-point tile

    // Per-lane component constants, in registers for the whole kernel.
    float mx[4], my[4], aa[4], cc[4];
    #pragma unroll
    for (int q = 0; q < 4; ++q) {
        const int k = j * 4 + q;
        const float s = fabsf(sigma[k]) + 1e-5f;
        mx[q] = mu[2 * k];
        my[q] = mu[2 * k + 1];
        aa[q] = -0.5f / (s * s);
        cc[q] = -2.0f * __logf(s) + NEG_D_HALF_LOG2PI;
    }

    float* __restrict__ mix_lp  = out;
    float* __restrict__ comp_lp = out + (size_t)N;
    const vf2* __restrict__ xp = (const vf2*)x;

    const int stride = gridDim.x * 128;  // 4 tiles of 32 points per block-iter

    for (int p0 = blockIdx.x * 128; p0 < N; p0 += stride) {
        int   p[4];
        bool  ok[4];
        vf2   xv[4];
        #pragma unroll
        for (int t = 0; t < 4; ++t) {
            p[t]  = p0 + t * 32 + pg;
            ok[t] = (p[t] < N);
            xv[t] = ok[t] ? __builtin_nontemporal_load(&xp[p[t]])
                          : (vf2){0.0f, 0.0f};
        }

        float comp[4][4];
        float m[4];
        #pragma unroll
        for (int t = 0; t < 4; ++t) {
            float mt = -INFINITY;
            #pragma unroll
            for (int q = 0; q < 4; ++q) {
                const float dx = xv[t].x - mx[q];
                const float dy = xv[t].y - my[q];
                const float v = fmaf(fmaf(dy, dy, dx * dx), aa[q], cc[q]);
                comp[t][q] = v;
                mt = fmaxf(mt, v);
            }
            m[t] = mt;
            // Bulk store enters the memory pipe immediately (regular store:
            // L2 write-back; wave writes 1KB contiguous per instruction).
            if (ok[t]) {
                vf4* dst = (vf4*)(comp_lp + (size_t)p[t] * 32 + j * 4);
                *dst = (vf4){comp[t][0], comp[t][1], comp[t][2], comp[t][3]};
            }
        }

        // Interleaved 8-lane butterfly reductions for the 4 tiles.
        #pragma unroll
        for (int d = 1; d <= 4; d <<= 1) {
            #pragma unroll
            for (int t = 0; t < 4; ++t)
                m[t] = fmaxf(m[t], __shfl_xor(m[t], d, 64));
        }

        float sum[4];
        #pragma unroll
        for (int t = 0; t < 4; ++t)
            sum[t] = __expf(comp[t][0] - m[t]) + __expf(comp[t][1] - m[t])
                   + __expf(comp[t][2] - m[t]) + __expf(comp[t][3] - m[t]);
        #pragma unroll
        for (int d = 1; d <= 4; d <<= 1) {
            #pragma unroll
            for (int t = 0; t < 4; ++t)
                sum[t] += __shfl_xor(sum[t], d, 64);
        }

        if (j == 0) {
            #pragma unroll
            for (int t = 0; t < 4; ++t)
                if (ok[t]) mix_lp[p[t]] = m[t] + __logf(sum[t]) - LOG_K;
        }
    }
}

extern "C" void kernel_launch(void* const* d_in, const int* in_sizes, int n_in,
                              void* d_out, int out_size, void* d_ws, size_t ws_size,
                              hipStream_t stream) {
    const float* x     = (const float*)d_in[0];
    const float* mu    = (const float*)d_in[1];
    const float* sigma = (const float*)d_in[2];
    float* out = (float*)d_out;

    const int N = in_sizes[0] / 2;  // inputs is (N, 2)

    const int block = 256;           // 128 points per block iteration
    const int grid = 2048;           // 8 blocks/CU, grid-stride (16 iters)

    gmm_kernel<<<grid, block, 0, stream>>>(x, mu, sigma, out, N);
}

// Round 5
// 140.935 us; speedup vs baseline: 1.0697x; 1.0697x over previous
//
#include <hip/hip_runtime.h>
#include <math.h>

// GaussianMixtureLayer: N=4194304 points (D=2), K=32 isotropic components.
// Outputs: mix_lp (N,) then comp_lp (N,32), concatenated float32.
// Memory-bound: ~587 MB traffic -> ~89 us floor at fill rate (6.6 TB/s).
//
// Layout: 8 lanes per point; lane j=tid&7 owns components 4j..4j+3 in regs.
// Thread i's comp_lp store address = base + 16B*i -> 1KB contiguous per wave.
// R5: NT stores restored (R4 de-confound: NT was the R3 win — 553MB stream
// doesn't fit L3, write-allocate thrashes it; NT commits straight through).
// 4 independent tiles/iter kept for store-pipeline depth under NT.

constexpr float NEG_D_HALF_LOG2PI = -1.8378770664093453f; // -0.5*D*log(2pi), D=2
constexpr float LOG_K = 3.4657359027997265f;              // log(32)

typedef float vf2 __attribute__((ext_vector_type(2)));
typedef float vf4 __attribute__((ext_vector_type(4)));

__global__ __launch_bounds__(256) void gmm_kernel(
    const float* __restrict__ x,      // (N,2)
    const float* __restrict__ mu,     // (32,2)
    const float* __restrict__ sigma,  // (32,1)
    float* __restrict__ out,          // mix_lp (N) ++ comp_lp (N*32)
    int N)
{
    const int tid = threadIdx.x;
    const int j   = tid & 7;    // component sub-group: owns k = 4j..4j+3
    const int pg  = tid >> 3;   // point index within a 32-point tile

    // Per-lane component constants, in registers for the whole kernel.
    float mx[4], my[4], aa[4], cc[4];
    #pragma unroll
    for (int q = 0; q < 4; ++q) {
        const int k = j * 4 + q;
        const float s = fabsf(sigma[k]) + 1e-5f;
        mx[q] = mu[2 * k];
        my[q] = mu[2 * k + 1];
        aa[q] = -0.5f / (s * s);
        cc[q] = -2.0f * __logf(s) + NEG_D_HALF_LOG2PI;
    }

    float* __restrict__ mix_lp  = out;
    float* __restrict__ comp_lp = out + (size_t)N;
    const vf2* __restrict__ xp = (const vf2*)x;

    const int stride = gridDim.x * 128;  // 4 tiles of 32 points per block-iter

    for (int p0 = blockIdx.x * 128; p0 < N; p0 += stride) {
        int   p[4];
        bool  ok[4];
        vf2   xv[4];
        #pragma unroll
        for (int t = 0; t < 4; ++t) {
            p[t]  = p0 + t * 32 + pg;
            ok[t] = (p[t] < N);
            xv[t] = ok[t] ? __builtin_nontemporal_load(&xp[p[t]])
                          : (vf2){0.0f, 0.0f};
        }

        float comp[4][4];
        float m[4];
        #pragma unroll
        for (int t = 0; t < 4; ++t) {
            float mt = -INFINITY;
            #pragma unroll
            for (int q = 0; q < 4; ++q) {
                const float dx = xv[t].x - mx[q];
                const float dy = xv[t].y - my[q];
                const float v = fmaf(fmaf(dy, dy, dx * dx), aa[q], cc[q]);
                comp[t][q] = v;
                mt = fmaxf(mt, v);
            }
            m[t] = mt;
            // Bulk NT store issues immediately: no cache allocation, wave
            // writes 1KB contiguous per instruction straight toward HBM.
            if (ok[t]) {
                vf4* dst = (vf4*)(comp_lp + (size_t)p[t] * 32 + j * 4);
                __builtin_nontemporal_store(
                    (vf4){comp[t][0], comp[t][1], comp[t][2], comp[t][3]}, dst);
            }
        }

        // Interleaved 8-lane butterfly reductions for the 4 tiles.
        #pragma unroll
        for (int d = 1; d <= 4; d <<= 1) {
            #pragma unroll
            for (int t = 0; t < 4; ++t)
                m[t] = fmaxf(m[t], __shfl_xor(m[t], d, 64));
        }

        float sum[4];
        #pragma unroll
        for (int t = 0; t < 4; ++t)
            sum[t] = __expf(comp[t][0] - m[t]) + __expf(comp[t][1] - m[t])
                   + __expf(comp[t][2] - m[t]) + __expf(comp[t][3] - m[t]);
        #pragma unroll
        for (int d = 1; d <= 4; d <<= 1) {
            #pragma unroll
            for (int t = 0; t < 4; ++t)
                sum[t] += __shfl_xor(sum[t], d, 64);
        }

        if (j == 0) {
            #pragma unroll
            for (int t = 0; t < 4; ++t)
                if (ok[t])
                    __builtin_nontemporal_store(
                        m[t] + __logf(sum[t]) - LOG_K, &mix_lp[p[t]]);
        }
    }
}

extern "C" void kernel_launch(void* const* d_in, const int* in_sizes, int n_in,
                              void* d_out, int out_size, void* d_ws, size_t ws_size,
                              hipStream_t stream) {
    const float* x     = (const float*)d_in[0];
    const float* mu    = (const float*)d_in[1];
    const float* sigma = (const float*)d_in[2];
    float* out = (float*)d_out;

    const int N = in_sizes[0] / 2;  // inputs is (N, 2)

    const int block = 256;           // 128 points per block iteration
    const int grid = 2048;           // 8 blocks/CU, grid-stride (16 iters)

    gmm_kernel<<<grid, block, 0, stream>>>(x, mu, sigma, out, N);
}

// Round 6
// 110.784 us; speedup vs baseline: 1.3609x; 1.2722x over previous
//
#include <hip/hip_runtime.h>
#include <math.h>

// GaussianMixtureLayer: N=4194304 points (D=2), K=32 isotropic components.
// Outputs: mix_lp (N,) then comp_lp (N,32), concatenated float32.
// Memory-bound: ~587 MB traffic -> ~89 us floor at fill rate (6.8 TB/s).
//
// Layout: 8 lanes per point; lane j=tid&7 owns components 4j..4j+3 in regs.
// Thread i's comp_lp store address = base + 16B*i -> 1KB contiguous per wave.
// R6: 8-lane reductions via DPP (quad_perm xor1/xor2 + row_half_mirror) --
// pure VALU, no DS pipe, ~2cyc/step vs ~40cyc ds_swizzle chains. x loads
// temporal (33.5MB sits in L3 across replays); mix_lp stores regular (L2
// merges 32B fragments); comp_lp bulk stores stay NT (553MB stream would
// thrash L3 -- proven +12us in R3/R4 de-confound).

constexpr float NEG_D_HALF_LOG2PI = -1.8378770664093453f; // -0.5*D*log(2pi), D=2
constexpr float LOG_K = 3.4657359027997265f;              // log(32)

typedef float vf2 __attribute__((ext_vector_type(2)));
typedef float vf4 __attribute__((ext_vector_type(4)));

// DPP cross-lane exchange within a 16-lane row (all our groups are 8-wide).
// 0xB1 = quad_perm [1,0,3,2] (xor1), 0x4E = quad_perm [2,3,0,1] (xor2),
// 0x141 = ROW_HALF_MIRROR (lane -> 7-lane within each 8-group, i.e. the
// other quad's reduced value after the two quad_perm steps).
template <int CTRL>
__device__ __forceinline__ float dpp_xchg(float v) {
    int s = __float_as_int(v);
    return __int_as_float(
        __builtin_amdgcn_update_dpp(s, s, CTRL, 0xF, 0xF, false));
}

__device__ __forceinline__ float grp8_max(float v) {
    v = fmaxf(v, dpp_xchg<0xB1>(v));
    v = fmaxf(v, dpp_xchg<0x4E>(v));
    v = fmaxf(v, dpp_xchg<0x141>(v));
    return v;
}

__device__ __forceinline__ float grp8_sum(float v) {
    v += dpp_xchg<0xB1>(v);
    v += dpp_xchg<0x4E>(v);
    v += dpp_xchg<0x141>(v);
    return v;
}

__global__ __launch_bounds__(256) void gmm_kernel(
    const float* __restrict__ x,      // (N,2)
    const float* __restrict__ mu,     // (32,2)
    const float* __restrict__ sigma,  // (32,1)
    float* __restrict__ out,          // mix_lp (N) ++ comp_lp (N*32)
    int N)
{
    const int tid = threadIdx.x;
    const int j   = tid & 7;    // component sub-group: owns k = 4j..4j+3
    const int pg  = tid >> 3;   // point index within a 32-point tile

    // Per-lane component constants, in registers for the whole kernel.
    float mx[4], my[4], aa[4], cc[4];
    #pragma unroll
    for (int q = 0; q < 4; ++q) {
        const int k = j * 4 + q;
        const float s = fabsf(sigma[k]) + 1e-5f;
        mx[q] = mu[2 * k];
        my[q] = mu[2 * k + 1];
        aa[q] = -0.5f / (s * s);
        cc[q] = -2.0f * __logf(s) + NEG_D_HALF_LOG2PI;
    }

    float* __restrict__ mix_lp  = out;
    float* __restrict__ comp_lp = out + (size_t)N;
    const vf2* __restrict__ xp = (const vf2*)x;

    const int stride = gridDim.x * 128;  // 4 tiles of 32 points per block-iter

    for (int p0 = blockIdx.x * 128; p0 < N; p0 += stride) {
        int   p[4];
        bool  ok[4];
        vf2   xv[4];
        #pragma unroll
        for (int t = 0; t < 4; ++t) {
            p[t]  = p0 + t * 32 + pg;
            ok[t] = (p[t] < N);
            xv[t] = ok[t] ? xp[p[t]] : (vf2){0.0f, 0.0f};  // temporal: L3-resident
        }

        float comp[4][4];
        float m[4];
        #pragma unroll
        for (int t = 0; t < 4; ++t) {
            float mt = -INFINITY;
            #pragma unroll
            for (int q = 0; q < 4; ++q) {
                const float dx = xv[t].x - mx[q];
                const float dy = xv[t].y - my[q];
                const float v = fmaf(fmaf(dy, dy, dx * dx), aa[q], cc[q]);
                comp[t][q] = v;
                mt = fmaxf(mt, v);
            }
            m[t] = mt;
            // Bulk NT store issues immediately: no cache allocation, wave
            // writes 1KB contiguous per instruction straight toward HBM.
            if (ok[t]) {
                vf4* dst = (vf4*)(comp_lp + (size_t)p[t] * 32 + j * 4);
                __builtin_nontemporal_store(
                    (vf4){comp[t][0], comp[t][1], comp[t][2], comp[t][3]}, dst);
            }
        }

        // Pure-VALU DPP butterflies (no DS pipe), 4 independent tiles.
        #pragma unroll
        for (int t = 0; t < 4; ++t) m[t] = grp8_max(m[t]);

        float sum[4];
        #pragma unroll
        for (int t = 0; t < 4; ++t)
            sum[t] = __expf(comp[t][0] - m[t]) + __expf(comp[t][1] - m[t])
                   + __expf(comp[t][2] - m[t]) + __expf(comp[t][3] - m[t]);
        #pragma unroll
        for (int t = 0; t < 4; ++t) sum[t] = grp8_sum(sum[t]);

        if (j == 0) {
            #pragma unroll
            for (int t = 0; t < 4; ++t)
                if (ok[t])  // regular store: L2 merges the 32B fragments
                    mix_lp[p[t]] = m[t] + __logf(sum[t]) - LOG_K;
        }
    }
}

extern "C" void kernel_launch(void* const* d_in, const int* in_sizes, int n_in,
                              void* d_out, int out_size, void* d_ws, size_t ws_size,
                              hipStream_t stream) {
    const float* x     = (const float*)d_in[0];
    const float* mu    = (const float*)d_in[1];
    const float* sigma = (const float*)d_in[2];
    float* out = (float*)d_out;

    const int N = in_sizes[0] / 2;  // inputs is (N, 2)

    const int block = 256;           // 128 points per block iteration
    const int grid = 2048;           // 8 blocks/CU, grid-stride (16 iters)

    gmm_kernel<<<grid, block, 0, stream>>>(x, mu, sigma, out, N);
}

// Round 7
// 110.418 us; speedup vs baseline: 1.3654x; 1.0033x over previous
//
#include <hip/hip_runtime.h>
#include <math.h>

// GaussianMixtureLayer: N=4194304 points (D=2), K=32 isotropic components.
// Outputs: mix_lp (N,) then comp_lp (N,32), concatenated float32.
// Memory-bound: ~604 MB traffic -> ~89-92 us floor at fill rate (6.6-6.8 TB/s).
//
// Layout: 8 lanes per point; lane j=tid&7 owns components 4j..4j+3 in regs.
// Thread i's comp_lp store address = base + 16B*i -> 1KB contiguous per wave.
// R7: occupancy probe. Unroll depth proven flat (R2~R4, R3~R5), so drop to
// 2 tiles/iter (~50 live VGPRs) + __launch_bounds__(256,8) to force <=64
// VGPR -> 8 waves/SIMD. Keep R6's proven config: DPP butterflies (no DS
// pipe), NT comp stores (553MB stream bypasses L3 -- R3/R4 de-confound),
// temporal x loads (33.5MB L3-resident), regular mix_lp stores (L2 merges
// the exec-masked 32B fragments).

constexpr float NEG_D_HALF_LOG2PI = -1.8378770664093453f; // -0.5*D*log(2pi), D=2
constexpr float LOG_K = 3.4657359027997265f;              // log(32)

typedef float vf2 __attribute__((ext_vector_type(2)));
typedef float vf4 __attribute__((ext_vector_type(4)));

// DPP cross-lane exchange: 0xB1 = quad_perm xor1, 0x4E = quad_perm xor2,
// 0x141 = ROW_HALF_MIRROR (completes the 8-wide butterfly).
template <int CTRL>
__device__ __forceinline__ float dpp_xchg(float v) {
    int s = __float_as_int(v);
    return __int_as_float(
        __builtin_amdgcn_update_dpp(s, s, CTRL, 0xF, 0xF, false));
}

__device__ __forceinline__ float grp8_max(float v) {
    v = fmaxf(v, dpp_xchg<0xB1>(v));
    v = fmaxf(v, dpp_xchg<0x4E>(v));
    v = fmaxf(v, dpp_xchg<0x141>(v));
    return v;
}

__device__ __forceinline__ float grp8_sum(float v) {
    v += dpp_xchg<0xB1>(v);
    v += dpp_xchg<0x4E>(v);
    v += dpp_xchg<0x141>(v);
    return v;
}

__global__ __launch_bounds__(256, 8) void gmm_kernel(
    const float* __restrict__ x,      // (N,2)
    const float* __restrict__ mu,     // (32,2)
    const float* __restrict__ sigma,  // (32,1)
    float* __restrict__ out,          // mix_lp (N) ++ comp_lp (N*32)
    int N)
{
    const int tid = threadIdx.x;
    const int j   = tid & 7;    // component sub-group: owns k = 4j..4j+3
    const int pg  = tid >> 3;   // point index within a 32-point tile

    // Per-lane component constants, in registers for the whole kernel.
    float mx[4], my[4], aa[4], cc[4];
    #pragma unroll
    for (int q = 0; q < 4; ++q) {
        const int k = j * 4 + q;
        const float s = fabsf(sigma[k]) + 1e-5f;
        mx[q] = mu[2 * k];
        my[q] = mu[2 * k + 1];
        aa[q] = -0.5f / (s * s);
        cc[q] = -2.0f * __logf(s) + NEG_D_HALF_LOG2PI;
    }

    float* __restrict__ mix_lp  = out;
    float* __restrict__ comp_lp = out + (size_t)N;
    const vf2* __restrict__ xp = (const vf2*)x;

    const int stride = gridDim.x * 64;  // 2 tiles of 32 points per block-iter

    for (int p0 = blockIdx.x * 64; p0 < N; p0 += stride) {
        int   p[2];
        bool  ok[2];
        vf2   xv[2];
        #pragma unroll
        for (int t = 0; t < 2; ++t) {
            p[t]  = p0 + t * 32 + pg;
            ok[t] = (p[t] < N);
            xv[t] = ok[t] ? xp[p[t]] : (vf2){0.0f, 0.0f};  // temporal: L3-resident
        }

        float comp[2][4];
        float m[2];
        #pragma unroll
        for (int t = 0; t < 2; ++t) {
            float mt = -INFINITY;
            #pragma unroll
            for (int q = 0; q < 4; ++q) {
                const float dx = xv[t].x - mx[q];
                const float dy = xv[t].y - my[q];
                const float v = fmaf(fmaf(dy, dy, dx * dx), aa[q], cc[q]);
                comp[t][q] = v;
                mt = fmaxf(mt, v);
            }
            m[t] = mt;
            // Bulk NT store issues immediately: wave writes 1KB contiguous
            // per instruction, no cache allocation.
            if (ok[t]) {
                vf4* dst = (vf4*)(comp_lp + (size_t)p[t] * 32 + j * 4);
                __builtin_nontemporal_store(
                    (vf4){comp[t][0], comp[t][1], comp[t][2], comp[t][3]}, dst);
            }
        }

        // Pure-VALU DPP butterflies (no DS pipe), 2 independent tiles.
        #pragma unroll
        for (int t = 0; t < 2; ++t) m[t] = grp8_max(m[t]);

        float sum[2];
        #pragma unroll
        for (int t = 0; t < 2; ++t)
            sum[t] = __expf(comp[t][0] - m[t]) + __expf(comp[t][1] - m[t])
                   + __expf(comp[t][2] - m[t]) + __expf(comp[t][3] - m[t]);
        #pragma unroll
        for (int t = 0; t < 2; ++t) sum[t] = grp8_sum(sum[t]);

        if (j == 0) {
            #pragma unroll
            for (int t = 0; t < 2; ++t)
                if (ok[t])  // regular store: L2 merges the 32B fragments
                    mix_lp[p[t]] = m[t] + __logf(sum[t]) - LOG_K;
        }
    }
}

extern "C" void kernel_launch(void* const* d_in, const int* in_sizes, int n_in,
                              void* d_out, int out_size, void* d_ws, size_t ws_size,
                              hipStream_t stream) {
    const float* x     = (const float*)d_in[0];
    const float* mu    = (const float*)d_in[1];
    const float* sigma = (const float*)d_in[2];
    float* out = (float*)d_out;

    const int N = in_sizes[0] / 2;  // inputs is (N, 2)

    const int block = 256;           // 64 points per block iteration
    const int grid = 2048;           // 8 blocks/CU, grid-stride (32 iters)

    gmm_kernel<<<grid, block, 0, stream>>>(x, mu, sigma, out, N);
}